// Round 15
// baseline (215.075 us; speedup 1.0000x reference)
//
#include <hip/hip_runtime.h>
#include <hip/hip_bf16.h>
#include <stdint.h>

#define MROWS 32
#define LDA   264   // Abuf stride in bf16 elems: 528 B/row (16B-aligned, bank-skewed)
#define FMS   40    // fmA stride in bf16 elems (80 B, 16B-aligned)

typedef __bf16 bf16x8 __attribute__((ext_vector_type(8)));
typedef float  f32x4  __attribute__((ext_vector_type(4)));
typedef float  f32x2  __attribute__((ext_vector_type(2)));

__device__ __forceinline__ unsigned short f2bf(float f) {
    union { float f; uint32_t u; } v; v.f = f;
    return (unsigned short)((v.u + 0x7FFFu + ((v.u >> 16) & 1u)) >> 16);
}

__device__ __forceinline__ ushort2 pk_bf16(float a, float b) {
    union { __hip_bfloat162 v; ushort2 u; } c;
    c.v = __float22bfloat162_rn(make_float2(a, b));
    return c.u;
}

// tanh-form GeLU via sigmoid on a float2 pair; muls/fmas lower to v_pk_* VOP3P,
// exp/rcp stay scalar transcendental. Max abs dev from exact-erf gelu ~3e-4.
__device__ __forceinline__ f32x2 gelu_fast2(f32x2 v) {
    const f32x2 t = v * v;
    f32x2 p = t * 0.044715f + 1.0f;
    const f32x2 u = v * p;
    f32x2 e;
    e.x = __builtin_amdgcn_exp2f(u.x * -2.3021131160186336f);  // exp(-2*0.79788456*u)
    e.y = __builtin_amdgcn_exp2f(u.y * -2.3021131160186336f);
    f32x2 r;
    r.x = __builtin_amdgcn_rcpf(1.0f + e.x);
    r.y = __builtin_amdgcn_rcpf(1.0f + e.y);
    return v * r;
}

// Fragment-order index map: f = w*64 + col*4 + j  <->  n = w*64 + j*16 + col.
__device__ __forceinline__ int frag_n(int f) {
    return (f & 0xC0) | ((f & 3) << 4) | ((f >> 2) & 15);
}

// prep1 (36 blocks, fully parallel, all-coalesced):
//  blocks 0..7: w1frag via LDS transpose (block kk: k in [kk*32,kk*32+32)) and,
//    fused on the same coalesced W1 row reads, partial gw1/b1t dot-products
//    -> gpart[kk][n], bpart[kk][n].
//  blocks 8..31: sqb row t = blk-8 in FRAGMENT order.
//  blocks 32..35: wfmfrag fragment-set f = blk-32 (K 16->32 zero-pad).
__global__ __launch_bounds__(256) void prep1(const float* __restrict__ W1,
                                             const float* __restrict__ step_q,
                                             const float* __restrict__ b_fm,
                                             const float* __restrict__ W_fm,
                                             const float* __restrict__ gamma,
                                             const float* __restrict__ beta,
                                             unsigned short* __restrict__ w1frag,
                                             float* __restrict__ sqb,
                                             unsigned short* __restrict__ wfmfrag,
                                             float* __restrict__ gpart,
                                             float* __restrict__ bpart) {
    const int blk = blockIdx.x, tid = threadIdx.x;
    if (blk < 8) {
        __shared__ unsigned short T[256][40];   // [n][k_local], rows 80B (16B-aligned)
        const int kk = blk;
        float sg = 0.f, sb = 0.f;
        #pragma unroll
        for (int r = 0; r < 32; ++r) {
            const int k = (kk << 5) + r;
            const float wv = W1[k * 256 + tid];        // coalesced row read
            sg = fmaf(gamma[k], wv, sg);
            sb = fmaf(beta[k],  wv, sb);
            T[tid][r] = f2bf(wv);
        }
        gpart[(kk << 8) + tid] = sg;
        bpart[(kk << 8) + tid] = sb;
        __syncthreads();
        #pragma unroll
        for (int f = 0; f < 4; ++f) {
            const int fi = (f << 8) + tid;             // 0..1023 = w*256 + j*64 + l
            const int l = fi & 63, j = (fi >> 6) & 3, w = fi >> 8;
            const int n = (w << 6) + (j << 4) + (l & 15);
            const uint4 v = *(const uint4*)&T[n][(l >> 4) << 3];  // 8 contiguous bf16
            *(uint4*)&w1frag[((w << 5) + (j << 3) + kk) * 512 + (l << 3)] = v;
        }
    } else if (blk < 32) {
        const int t = blk - 8;
        const int n = frag_n(tid);
        sqb[t * 256 + tid] = step_q[t * 256 + n] + b_fm[n];
    } else {
        const int f  = blk - 32;                       // 0..3
        const int fr = (f << 8) + tid;
        const int l = fr & 63, j = (fr >> 6) & 3, w = fr >> 8;
        const int n = (w << 6) + (j << 4) + (l & 15);
        const int qr = l >> 4;
        #pragma unroll
        for (int e = 0; e < 8; ++e) {
            const int k = (qr << 3) + e;
            wfmfrag[(fr << 3) + e] = (k < 16) ? f2bf(W_fm[(k << 8) + n]) : (unsigned short)0;
        }
    }
}

// prep2 (1 block): reduce gpart/bpart and emit epilogue tables in FRAGMENT order.
__global__ __launch_bounds__(256) void prep2(const float* __restrict__ gpart,
                                             const float* __restrict__ bpart,
                                             const float* __restrict__ b1,
                                             const float* __restrict__ W2,
                                             const float* __restrict__ gamma,
                                             float* __restrict__ gw1f,
                                             float* __restrict__ b1tf,
                                             float* __restrict__ w2f,
                                             float* __restrict__ gamf) {
    const int tid = threadIdx.x;
    const int n = frag_n(tid);
    float sg = 0.f, sb = 0.f;
    #pragma unroll
    for (int kk = 0; kk < 8; ++kk) {
        sg += gpart[(kk << 8) + n];
        sb += bpart[(kk << 8) + n];
    }
    gw1f[tid] = sg;
    b1tf[tid] = sb + b1[n];
    w2f[tid]  = W2[n];
    gamf[tid] = gamma[n];
}

__global__ __launch_bounds__(256, 6) void fused_head(
    const float* __restrict__ final_h, const float* __restrict__ future_met,
    const float* __restrict__ b2,      const unsigned short* __restrict__ w1frag,
    const float* __restrict__ sqb,     const unsigned short* __restrict__ wfmfrag,
    const float* __restrict__ gw1f,    const float* __restrict__ b1tf,
    const float* __restrict__ w2f,     const float* __restrict__ gamf,
    float* __restrict__ out)
{
    __shared__ __align__(16) unsigned short Abuf[MROWS * LDA];  // 16896 B
    __shared__ __align__(16) unsigned short fmA[MROWS * FMS];   //  2560 B
    __shared__ float2 red[4][MROWS];                            //  1024 B
    __shared__ float2 mv[MROWS];                                //   256 B
    __shared__ float  part[4][MROWS];                           //   512 B

    const int tid = threadIdx.x;
    const int w   = tid >> 6;
    const int l   = tid & 63;
    const int col = l & 15;
    const int qr  = l >> 4;
    const int m0  = blockIdx.x * MROWS;
    const int bn0 = m0 / 24;            // one magic-div per thread
    const int tt0 = m0 - bn0 * 24;
    const int fb  = (w << 6) + (col << 2);   // fragment-table base for this thread

    // ---- stage fm rows as bf16 (k 0..15), zero-pad k 16..31 ----
    if (tid < 128) {
        const int row = tid >> 2, f0 = (tid & 3) << 2;
        const int tta = tt0 + row;
        const int sub = (tta >= 24) + (tta >= 48);
        const int tt  = tta - sub * 24;
        const int bn  = bn0 + sub;
        const int b   = bn / 1000, n = bn - b * 1000;
        const float4 v = *(const float4*)&future_met[((((b * 24 + tt) * 1000) + n) << 4) + f0];
        ushort2 lo = pk_bf16(v.x, v.y), hi = pk_bf16(v.z, v.w);
        ushort4 o; o.x = lo.x; o.y = lo.y; o.z = hi.x; o.w = hi.y;
        *(ushort4*)&fmA[row * FMS + f0] = o;
    }
    {
        const int row = tid >> 3, k = 16 + ((tid & 7) << 1);
        *(unsigned int*)&fmA[row * FMS + k] = 0u;
    }
    __syncthreads();

    // gamma prefetch (fragment-order float4), as packed pairs
    const float4 g4 = *(const float4*)&gamf[fb];
    const f32x2 gA2 = {g4.x, g4.y}, gB2 = {g4.z, g4.w};

    // ---- phase A: acc = final_h + (step_q + b_fm), MFMA C layout ----
    // This lane's 8 rows span d = qr*4 .. qr*4+19 (< 24), so at most TWO
    // distinct bn rows of final_h are touched: load both once, select per (i,r).
    const int dlo = qr << 2;
    const int slo = ((tt0 + dlo) >= 24) + ((tt0 + dlo) >= 48);
    const int shi = ((tt0 + dlo + 19) >= 24) + ((tt0 + dlo + 19) >= 48);
    float flo[4], fhi[4];
    {
        const float* fhl = final_h + ((bn0 + slo) << 8) + (w << 6) + col;
        const float* fhh = final_h + ((bn0 + shi) << 8) + (w << 6) + col;
        #pragma unroll
        for (int j = 0; j < 4; ++j) { flo[j] = fhl[j << 4]; fhi[j] = fhh[j << 4]; }
    }

    f32x4 acc[2][4];
    #pragma unroll
    for (int i = 0; i < 2; ++i) {
        #pragma unroll
        for (int r = 0; r < 4; ++r) {
            const int d   = (i << 4) + (qr << 2) + r;
            const int tta = tt0 + d;
            const int sub = (tta >= 24) + (tta >= 48);
            const int tt  = tta - sub * 24;
            const bool lo = (sub == slo);
            const float4 sb4 = *(const float4*)&sqb[(tt << 8) + fb];
            acc[i][0][r] = (lo ? flo[0] : fhi[0]) + sb4.x;
            acc[i][1][r] = (lo ? flo[1] : fhi[1]) + sb4.y;
            acc[i][2][r] = (lo ? flo[2] : fhi[2]) + sb4.z;
            acc[i][3][r] = (lo ? flo[3] : fhi[3]) + sb4.w;
        }
    }
    // fm @ W_fm via MFMA (K=32, upper half zeros)
    {
        const bf16x8 af0 = *(const bf16x8*)&fmA[col * FMS + (qr << 3)];
        const bf16x8 af1 = *(const bf16x8*)&fmA[(16 + col) * FMS + (qr << 3)];
        const unsigned short* Bwf = wfmfrag + (w << 11) + (l << 3);
        #pragma unroll
        for (int j = 0; j < 4; ++j) {
            const bf16x8 bf = *(const bf16x8*)(Bwf + (j << 9));
            acc[0][j] = __builtin_amdgcn_mfma_f32_16x16x32_bf16(af0, bf, acc[0][j], 0, 0, 0);
            acc[1][j] = __builtin_amdgcn_mfma_f32_16x16x32_bf16(af1, bf, acc[1][j], 0, 0, 0);
        }
    }

    // ---- stats + gamma-scaled bf16 A-tile (packed-f32 pairs; no mean before MFMA) ----
    #pragma unroll
    for (int i = 0; i < 2; ++i) {
        #pragma unroll
        for (int r = 0; r < 4; ++r) {
            const int m = (i << 4) + (qr << 2) + r;
            const f32x2 vA = {acc[i][0][r], acc[i][1][r]};
            const f32x2 vB = {acc[i][2][r], acc[i][3][r]};
            const f32x2 sv = vA + vB;                 // v_pk_add
            const f32x2 qv = vA * vA + vB * vB;       // v_pk_mul + v_pk_fma
            float s = sv.x + sv.y;
            float q = qv.x + qv.y;
            const f32x2 vjA = vA * gA2;               // v_pk_mul
            const f32x2 vjB = vB * gB2;
            s += __shfl_xor(s, 1); q += __shfl_xor(q, 1);
            s += __shfl_xor(s, 2); q += __shfl_xor(q, 2);
            s += __shfl_xor(s, 4); q += __shfl_xor(q, 4);
            s += __shfl_xor(s, 8); q += __shfl_xor(q, 8);
            if (col == 0) red[w][m] = make_float2(s, q);
            const ushort2 p01 = pk_bf16(vjA.x, vjA.y);
            const ushort2 p23 = pk_bf16(vjB.x, vjB.y);
            unsigned short* Ab = &Abuf[m * LDA + (w << 6) + col];
            Ab[0]  = p01.x; Ab[16] = p01.y;
            Ab[32] = p23.x; Ab[48] = p23.y;
        }
    }
    __syncthreads();   // Abuf + red ready

    if (tid < MROWS) {
        const float2 a0 = red[0][tid], a1 = red[1][tid], a2 = red[2][tid], a3 = red[3][tid];
        const float S = a0.x + a1.x + a2.x + a3.x;
        const float Q = a0.y + a1.y + a2.y + a3.y;
        const float mu = S * 0.00390625f;
        const float rstd = rsqrtf(Q * 0.00390625f - mu * mu + 1e-5f);
        mv[tid] = make_float2(mu, rstd);
    }

    // ---- phase 2: (32x256) @ W1 via MFMA (overlaps the mv computation) ----
    #pragma unroll
    for (int i = 0; i < 2; ++i)
        #pragma unroll
        for (int j = 0; j < 4; ++j)
            acc[i][j] = (f32x4){0.f, 0.f, 0.f, 0.f};

    {
        const unsigned short* Bw  = w1frag + (w << 14) + (l << 3);
        const unsigned short* Ab0 = &Abuf[col * LDA + (qr << 3)];
        const unsigned short* Ab1 = &Abuf[(16 + col) * LDA + (qr << 3)];
        #pragma unroll
        for (int kk = 0; kk < 8; ++kk) {
            const bf16x8 a0 = *(const bf16x8*)(Ab0 + (kk << 5));
            const bf16x8 a1 = *(const bf16x8*)(Ab1 + (kk << 5));
            #pragma unroll
            for (int j = 0; j < 4; ++j) {
                const bf16x8 bf = *(const bf16x8*)(Bw + (j << 12) + (kk << 9));
                acc[0][j] = __builtin_amdgcn_mfma_f32_16x16x32_bf16(a0, bf, acc[0][j], 0, 0, 0);
                acc[1][j] = __builtin_amdgcn_mfma_f32_16x16x32_bf16(a1, bf, acc[1][j], 0, 0, 0);
            }
        }
    }

    // epilogue vector prefetch (fragment-order float4 tables), as packed pairs
    const float4 gw4 = *(const float4*)&gw1f[fb];
    const float4 bt4 = *(const float4*)&b1tf[fb];
    const float4 w24 = *(const float4*)&w2f[fb];
    const f32x2 gwA = {gw4.x, gw4.y}, gwB = {gw4.z, gw4.w};
    const f32x2 btA = {bt4.x, bt4.y}, btB = {bt4.z, bt4.w};
    const f32x2 w2A = {w24.x, w24.y}, w2B = {w24.z, w24.w};
    __syncthreads();   // mv visible to all waves

    // ---- epilogue: y = rstd*acc + (-mu*rstd)*gw1 + b1t; gelu; dot W2; reduce ----
    #pragma unroll
    for (int i = 0; i < 2; ++i) {
        #pragma unroll
        for (int r = 0; r < 4; ++r) {
            const int m = (i << 4) + (qr << 2) + r;
            const float2 p = mv[m];
            const float cm = -p.x * p.y;
            const f32x2 baseA = gwA * cm + btA;       // v_pk_fma
            const f32x2 baseB = gwB * cm + btB;
            const f32x2 accA = {acc[i][0][r], acc[i][1][r]};
            const f32x2 accB = {acc[i][2][r], acc[i][3][r]};
            const f32x2 yA = accA * p.y + baseA;      // v_pk_fma
            const f32x2 yB = accB * p.y + baseB;
            const f32x2 gvA = gelu_fast2(yA);
            const f32x2 gvB = gelu_fast2(yB);
            const f32x2 pp2 = gvA * w2A + gvB * w2B;  // v_pk_mul + v_pk_fma
            float pp = pp2.x + pp2.y;
            pp += __shfl_xor(pp, 1);
            pp += __shfl_xor(pp, 2);
            pp += __shfl_xor(pp, 4);
            pp += __shfl_xor(pp, 8);
            if (col == 0) part[w][m] = pp;
        }
    }
    __syncthreads();

    if (tid < MROWS) {
        const int m = m0 + tid;
        const float val = part[0][tid] + part[1][tid] + part[2][tid] + part[3][tid] + b2[0];
        const int bn = m / 24, tt = m - bn * 24;
        const int b  = bn / 1000, n = bn - b * 1000;
        out[(b * 24 + tt) * 1000 + n] = val;
    }
}

extern "C" void kernel_launch(void* const* d_in, const int* in_sizes, int n_in,
                              void* d_out, int out_size, void* d_ws, size_t ws_size,
                              hipStream_t stream) {
    const float* final_h    = (const float*)d_in[0];
    const float* future_met = (const float*)d_in[1];
    const float* step_q     = (const float*)d_in[2];
    const float* W_fm       = (const float*)d_in[3];
    const float* b_fm       = (const float*)d_in[4];
    const float* gamma      = (const float*)d_in[5];
    const float* beta       = (const float*)d_in[6];
    const float* W1         = (const float*)d_in[7];
    const float* b1         = (const float*)d_in[8];
    const float* W2         = (const float*)d_in[9];
    const float* b2         = (const float*)d_in[10];

    unsigned short* w1frag  = (unsigned short*)d_ws;                    // 131072 B
    float*          sqb     = (float*)((char*)d_ws + 131072);           //  24576 B
    unsigned short* wfmfrag = (unsigned short*)((char*)d_ws + 155648);  //  32768 B
    float*          gpart   = (float*)((char*)d_ws + 188416);           //   8192 B
    float*          bpart   = (float*)((char*)d_ws + 196608);           //   8192 B
    float*          gw1f    = (float*)((char*)d_ws + 204800);           //   1024 B
    float*          b1tf    = (float*)((char*)d_ws + 205824);           //   1024 B
    float*          w2f     = (float*)((char*)d_ws + 206848);           //   1024 B
    float*          gamf    = (float*)((char*)d_ws + 207872);           //   1024 B
    float* out = (float*)d_out;

    prep1<<<36, 256, 0, stream>>>(W1, step_q, b_fm, W_fm, gamma, beta,
                                  w1frag, sqb, wfmfrag, gpart, bpart);
    prep2<<<1, 256, 0, stream>>>(gpart, bpart, b1, W2, gamma, gw1f, b1tf, w2f, gamf);
    fused_head<<<12000, 256, 0, stream>>>(final_h, future_met, b2,
                                          w1frag, sqb, wfmfrag, gw1f, b1tf, w2f, gamf, out);
}

// Round 16
// 205.492 us; speedup vs baseline: 1.0466x; 1.0466x over previous
//
#include <hip/hip_runtime.h>
#include <hip/hip_bf16.h>
#include <stdint.h>

#define MROWS 32
#define LDA   264   // Abuf stride in bf16 elems: 528 B/row (16B-aligned, bank-skewed)
#define FMS   40    // fmA stride in bf16 elems (80 B, 16B-aligned)

typedef __bf16 bf16x8 __attribute__((ext_vector_type(8)));
typedef float  f32x4  __attribute__((ext_vector_type(4)));
typedef float  f32x2  __attribute__((ext_vector_type(2)));

__device__ __forceinline__ unsigned short f2bf(float f) {
    union { float f; uint32_t u; } v; v.f = f;
    return (unsigned short)((v.u + 0x7FFFu + ((v.u >> 16) & 1u)) >> 16);
}

__device__ __forceinline__ ushort2 pk_bf16(float a, float b) {
    union { __hip_bfloat162 v; ushort2 u; } c;
    c.v = __float22bfloat162_rn(make_float2(a, b));
    return c.u;
}

// DPP row-reduction step on the VALU pipe (no DS): x += row_shr<N>(x),
// bound_ctrl=1 -> cross-row sources read 0 (sum identity). After steps
// 1,2,4,8 lane col==15 of each 16-lane row holds the full row sum.
template <int CTRL>
__device__ __forceinline__ float dpp_radd(float x) {
    union { float f; int i; } a, b;
    a.f = x;
    b.i = __builtin_amdgcn_update_dpp(0, a.i, CTRL, 0xF, 0xF, true);
    return x + b.f;
}
#define ROW_SHR1 0x111
#define ROW_SHR2 0x112
#define ROW_SHR4 0x114
#define ROW_SHR8 0x118
__device__ __forceinline__ float dpp_rowsum(float x) {
    x = dpp_radd<ROW_SHR1>(x);
    x = dpp_radd<ROW_SHR2>(x);
    x = dpp_radd<ROW_SHR4>(x);
    x = dpp_radd<ROW_SHR8>(x);
    return x;   // valid in lane col==15 of each row
}

// tanh-form GeLU via sigmoid on a float2 pair; muls/fmas lower to v_pk_* VOP3P.
__device__ __forceinline__ f32x2 gelu_fast2(f32x2 v) {
    const f32x2 t = v * v;
    f32x2 p = t * 0.044715f + 1.0f;
    const f32x2 u = v * p;
    f32x2 e;
    e.x = __builtin_amdgcn_exp2f(u.x * -2.3021131160186336f);  // exp(-2*0.79788456*u)
    e.y = __builtin_amdgcn_exp2f(u.y * -2.3021131160186336f);
    f32x2 r;
    r.x = __builtin_amdgcn_rcpf(1.0f + e.x);
    r.y = __builtin_amdgcn_rcpf(1.0f + e.y);
    return v * r;
}

// Fragment-order index map: f = w*64 + col*4 + j  <->  n = w*64 + j*16 + col.
__device__ __forceinline__ int frag_n(int f) {
    return (f & 0xC0) | ((f & 3) << 4) | ((f >> 2) & 15);
}

// prep1 (36 blocks, fully parallel, all-coalesced).
__global__ __launch_bounds__(256) void prep1(const float* __restrict__ W1,
                                             const float* __restrict__ step_q,
                                             const float* __restrict__ b_fm,
                                             const float* __restrict__ W_fm,
                                             const float* __restrict__ gamma,
                                             const float* __restrict__ beta,
                                             unsigned short* __restrict__ w1frag,
                                             float* __restrict__ sqb,
                                             unsigned short* __restrict__ wfmfrag,
                                             float* __restrict__ gpart,
                                             float* __restrict__ bpart) {
    const int blk = blockIdx.x, tid = threadIdx.x;
    if (blk < 8) {
        __shared__ unsigned short T[256][40];   // [n][k_local], rows 80B (16B-aligned)
        const int kk = blk;
        float sg = 0.f, sb = 0.f;
        #pragma unroll
        for (int r = 0; r < 32; ++r) {
            const int k = (kk << 5) + r;
            const float wv = W1[k * 256 + tid];        // coalesced row read
            sg = fmaf(gamma[k], wv, sg);
            sb = fmaf(beta[k],  wv, sb);
            T[tid][r] = f2bf(wv);
        }
        gpart[(kk << 8) + tid] = sg;
        bpart[(kk << 8) + tid] = sb;
        __syncthreads();
        #pragma unroll
        for (int f = 0; f < 4; ++f) {
            const int fi = (f << 8) + tid;             // 0..1023 = w*256 + j*64 + l
            const int l = fi & 63, j = (fi >> 6) & 3, w = fi >> 8;
            const int n = (w << 6) + (j << 4) + (l & 15);
            const uint4 v = *(const uint4*)&T[n][(l >> 4) << 3];  // 8 contiguous bf16
            *(uint4*)&w1frag[((w << 5) + (j << 3) + kk) * 512 + (l << 3)] = v;
        }
    } else if (blk < 32) {
        const int t = blk - 8;
        const int n = frag_n(tid);
        sqb[t * 256 + tid] = step_q[t * 256 + n] + b_fm[n];
    } else {
        const int f  = blk - 32;                       // 0..3
        const int fr = (f << 8) + tid;
        const int l = fr & 63, j = (fr >> 6) & 3, w = fr >> 8;
        const int n = (w << 6) + (j << 4) + (l & 15);
        const int qr = l >> 4;
        #pragma unroll
        for (int e = 0; e < 8; ++e) {
            const int k = (qr << 3) + e;
            wfmfrag[(fr << 3) + e] = (k < 16) ? f2bf(W_fm[(k << 8) + n]) : (unsigned short)0;
        }
    }
}

// prep2 (1 block): reduce gpart/bpart and emit epilogue tables in FRAGMENT order.
__global__ __launch_bounds__(256) void prep2(const float* __restrict__ gpart,
                                             const float* __restrict__ bpart,
                                             const float* __restrict__ b1,
                                             const float* __restrict__ W2,
                                             const float* __restrict__ gamma,
                                             float* __restrict__ gw1f,
                                             float* __restrict__ b1tf,
                                             float* __restrict__ w2f,
                                             float* __restrict__ gamf) {
    const int tid = threadIdx.x;
    const int n = frag_n(tid);
    float sg = 0.f, sb = 0.f;
    #pragma unroll
    for (int kk = 0; kk < 8; ++kk) {
        sg += gpart[(kk << 8) + n];
        sb += bpart[(kk << 8) + n];
    }
    gw1f[tid] = sg;
    b1tf[tid] = sb + b1[n];
    w2f[tid]  = W2[n];
    gamf[tid] = gamma[n];
}

__global__ __launch_bounds__(256, 6) void fused_head(
    const float* __restrict__ final_h, const float* __restrict__ future_met,
    const float* __restrict__ b2,      const unsigned short* __restrict__ w1frag,
    const float* __restrict__ sqb,     const unsigned short* __restrict__ wfmfrag,
    const float* __restrict__ gw1f,    const float* __restrict__ b1tf,
    const float* __restrict__ w2f,     const float* __restrict__ gamf,
    float* __restrict__ out)
{
    __shared__ __align__(16) unsigned short Abuf[MROWS * LDA];  // 16896 B
    __shared__ __align__(16) unsigned short fmA[MROWS * FMS];   //  2560 B
    __shared__ float2 red[4][MROWS];                            //  1024 B
    __shared__ float2 mv[MROWS];                                //   256 B
    __shared__ float  part[4][MROWS];                           //   512 B

    const int tid = threadIdx.x;
    const int w   = tid >> 6;
    const int l   = tid & 63;
    const int col = l & 15;
    const int qr  = l >> 4;
    const int m0  = blockIdx.x * MROWS;
    const int bn0 = m0 / 24;            // one magic-div per thread
    const int tt0 = m0 - bn0 * 24;
    const int fb  = (w << 6) + (col << 2);   // fragment-table base for this thread

    // ---- stage fm rows as bf16 (k 0..15), zero-pad k 16..31 ----
    if (tid < 128) {
        const int row = tid >> 2, f0 = (tid & 3) << 2;
        const int tta = tt0 + row;
        const int sub = (tta >= 24) + (tta >= 48);
        const int tt  = tta - sub * 24;
        const int bn  = bn0 + sub;
        const int b   = bn / 1000, n = bn - b * 1000;
        const float4 v = *(const float4*)&future_met[((((b * 24 + tt) * 1000) + n) << 4) + f0];
        ushort2 lo = pk_bf16(v.x, v.y), hi = pk_bf16(v.z, v.w);
        ushort4 o; o.x = lo.x; o.y = lo.y; o.z = hi.x; o.w = hi.y;
        *(ushort4*)&fmA[row * FMS + f0] = o;
    }
    {
        const int row = tid >> 3, k = 16 + ((tid & 7) << 1);
        *(unsigned int*)&fmA[row * FMS + k] = 0u;
    }
    __syncthreads();

    // gamma prefetch (fragment-order float4), as packed pairs
    const float4 g4 = *(const float4*)&gamf[fb];
    const f32x2 gA2 = {g4.x, g4.y}, gB2 = {g4.z, g4.w};

    // ---- phase A: acc = final_h + (step_q + b_fm), MFMA C layout ----
    const int dlo = qr << 2;
    const int slo = ((tt0 + dlo) >= 24) + ((tt0 + dlo) >= 48);
    const int shi = ((tt0 + dlo + 19) >= 24) + ((tt0 + dlo + 19) >= 48);
    float flo[4], fhi[4];
    {
        const float* fhl = final_h + ((bn0 + slo) << 8) + (w << 6) + col;
        const float* fhh = final_h + ((bn0 + shi) << 8) + (w << 6) + col;
        #pragma unroll
        for (int j = 0; j < 4; ++j) { flo[j] = fhl[j << 4]; fhi[j] = fhh[j << 4]; }
    }

    f32x4 acc[2][4];
    #pragma unroll
    for (int i = 0; i < 2; ++i) {
        #pragma unroll
        for (int r = 0; r < 4; ++r) {
            const int d   = (i << 4) + (qr << 2) + r;
            const int tta = tt0 + d;
            const int sub = (tta >= 24) + (tta >= 48);
            const int tt  = tta - sub * 24;
            const bool lo = (sub == slo);
            const float4 sb4 = *(const float4*)&sqb[(tt << 8) + fb];
            acc[i][0][r] = (lo ? flo[0] : fhi[0]) + sb4.x;
            acc[i][1][r] = (lo ? flo[1] : fhi[1]) + sb4.y;
            acc[i][2][r] = (lo ? flo[2] : fhi[2]) + sb4.z;
            acc[i][3][r] = (lo ? flo[3] : fhi[3]) + sb4.w;
        }
    }
    // fm @ W_fm via MFMA (K=32, upper half zeros)
    {
        const bf16x8 af0 = *(const bf16x8*)&fmA[col * FMS + (qr << 3)];
        const bf16x8 af1 = *(const bf16x8*)&fmA[(16 + col) * FMS + (qr << 3)];
        const unsigned short* Bwf = wfmfrag + (w << 11) + (l << 3);
        #pragma unroll
        for (int j = 0; j < 4; ++j) {
            const bf16x8 bf = *(const bf16x8*)(Bwf + (j << 9));
            acc[0][j] = __builtin_amdgcn_mfma_f32_16x16x32_bf16(af0, bf, acc[0][j], 0, 0, 0);
            acc[1][j] = __builtin_amdgcn_mfma_f32_16x16x32_bf16(af1, bf, acc[1][j], 0, 0, 0);
        }
    }

    // ---- stats (DPP row-sum on VALU pipe) + gamma-scaled bf16 A-tile ----
    #pragma unroll
    for (int i = 0; i < 2; ++i) {
        #pragma unroll
        for (int r = 0; r < 4; ++r) {
            const int m = (i << 4) + (qr << 2) + r;
            const f32x2 vA = {acc[i][0][r], acc[i][1][r]};
            const f32x2 vB = {acc[i][2][r], acc[i][3][r]};
            const f32x2 sv = vA + vB;                 // v_pk_add
            const f32x2 qv = vA * vA + vB * vB;       // v_pk_mul + v_pk_fma
            float s = sv.x + sv.y;
            float q = qv.x + qv.y;
            const f32x2 vjA = vA * gA2;               // v_pk_mul
            const f32x2 vjB = vB * gB2;
            s = dpp_rowsum(s);                        // VALU, not DS
            q = dpp_rowsum(q);
            if (col == 15) red[w][m] = make_float2(s, q);
            const ushort2 p01 = pk_bf16(vjA.x, vjA.y);
            const ushort2 p23 = pk_bf16(vjB.x, vjB.y);
            unsigned short* Ab = &Abuf[m * LDA + (w << 6) + col];
            Ab[0]  = p01.x; Ab[16] = p01.y;
            Ab[32] = p23.x; Ab[48] = p23.y;
        }
    }
    __syncthreads();   // Abuf + red ready

    if (tid < MROWS) {
        const float2 a0 = red[0][tid], a1 = red[1][tid], a2 = red[2][tid], a3 = red[3][tid];
        const float S = a0.x + a1.x + a2.x + a3.x;
        const float Q = a0.y + a1.y + a2.y + a3.y;
        const float mu = S * 0.00390625f;
        const float rstd = rsqrtf(Q * 0.00390625f - mu * mu + 1e-5f);
        mv[tid] = make_float2(mu, rstd);
    }

    // ---- phase 2: (32x256) @ W1 via MFMA (overlaps the mv computation) ----
    #pragma unroll
    for (int i = 0; i < 2; ++i)
        #pragma unroll
        for (int j = 0; j < 4; ++j)
            acc[i][j] = (f32x4){0.f, 0.f, 0.f, 0.f};

    {
        const unsigned short* Bw  = w1frag + (w << 14) + (l << 3);
        const unsigned short* Ab0 = &Abuf[col * LDA + (qr << 3)];
        const unsigned short* Ab1 = &Abuf[(16 + col) * LDA + (qr << 3)];
        #pragma unroll
        for (int kk = 0; kk < 8; ++kk) {
            const bf16x8 a0 = *(const bf16x8*)(Ab0 + (kk << 5));
            const bf16x8 a1 = *(const bf16x8*)(Ab1 + (kk << 5));
            #pragma unroll
            for (int j = 0; j < 4; ++j) {
                const bf16x8 bf = *(const bf16x8*)(Bw + (j << 12) + (kk << 9));
                acc[0][j] = __builtin_amdgcn_mfma_f32_16x16x32_bf16(a0, bf, acc[0][j], 0, 0, 0);
                acc[1][j] = __builtin_amdgcn_mfma_f32_16x16x32_bf16(a1, bf, acc[1][j], 0, 0, 0);
            }
        }
    }

    // epilogue vector prefetch (fragment-order float4 tables), as packed pairs
    const float4 gw4 = *(const float4*)&gw1f[fb];
    const float4 bt4 = *(const float4*)&b1tf[fb];
    const float4 w24 = *(const float4*)&w2f[fb];
    const f32x2 gwA = {gw4.x, gw4.y}, gwB = {gw4.z, gw4.w};
    const f32x2 btA = {bt4.x, bt4.y}, btB = {bt4.z, bt4.w};
    const f32x2 w2A = {w24.x, w24.y}, w2B = {w24.z, w24.w};
    __syncthreads();   // mv visible to all waves

    // ---- epilogue: y = rstd*acc + (-mu*rstd)*gw1 + b1t; gelu; dot W2; DPP reduce ----
    #pragma unroll
    for (int i = 0; i < 2; ++i) {
        #pragma unroll
        for (int r = 0; r < 4; ++r) {
            const int m = (i << 4) + (qr << 2) + r;
            const float2 p = mv[m];
            const float cm = -p.x * p.y;
            const f32x2 baseA = gwA * cm + btA;       // v_pk_fma
            const f32x2 baseB = gwB * cm + btB;
            const f32x2 accA = {acc[i][0][r], acc[i][1][r]};
            const f32x2 accB = {acc[i][2][r], acc[i][3][r]};
            const f32x2 yA = accA * p.y + baseA;      // v_pk_fma
            const f32x2 yB = accB * p.y + baseB;
            const f32x2 gvA = gelu_fast2(yA);
            const f32x2 gvB = gelu_fast2(yB);
            const f32x2 pp2 = gvA * w2A + gvB * w2B;  // v_pk_mul + v_pk_fma
            float pp = pp2.x + pp2.y;
            pp = dpp_rowsum(pp);                      // VALU, not DS
            if (col == 15) part[w][m] = pp;
        }
    }
    __syncthreads();

    if (tid < MROWS) {
        const int m = m0 + tid;
        const float val = part[0][tid] + part[1][tid] + part[2][tid] + part[3][tid] + b2[0];
        const int bn = m / 24, tt = m - bn * 24;
        const int b  = bn / 1000, n = bn - b * 1000;
        out[(b * 24 + tt) * 1000 + n] = val;
    }
}

extern "C" void kernel_launch(void* const* d_in, const int* in_sizes, int n_in,
                              void* d_out, int out_size, void* d_ws, size_t ws_size,
                              hipStream_t stream) {
    const float* final_h    = (const float*)d_in[0];
    const float* future_met = (const float*)d_in[1];
    const float* step_q     = (const float*)d_in[2];
    const float* W_fm       = (const float*)d_in[3];
    const float* b_fm       = (const float*)d_in[4];
    const float* gamma      = (const float*)d_in[5];
    const float* beta       = (const float*)d_in[6];
    const float* W1         = (const float*)d_in[7];
    const float* b1         = (const float*)d_in[8];
    const float* W2         = (const float*)d_in[9];
    const float* b2         = (const float*)d_in[10];

    unsigned short* w1frag  = (unsigned short*)d_ws;                    // 131072 B
    float*          sqb     = (float*)((char*)d_ws + 131072);           //  24576 B
    unsigned short* wfmfrag = (unsigned short*)((char*)d_ws + 155648);  //  32768 B
    float*          gpart   = (float*)((char*)d_ws + 188416);           //   8192 B
    float*          bpart   = (float*)((char*)d_ws + 196608);           //   8192 B
    float*          gw1f    = (float*)((char*)d_ws + 204800);           //   1024 B
    float*          b1tf    = (float*)((char*)d_ws + 205824);           //   1024 B
    float*          w2f     = (float*)((char*)d_ws + 206848);           //   1024 B
    float*          gamf    = (float*)((char*)d_ws + 207872);           //   1024 B
    float* out = (float*)d_out;

    prep1<<<36, 256, 0, stream>>>(W1, step_q, b_fm, W_fm, gamma, beta,
                                  w1frag, sqb, wfmfrag, gpart, bpart);
    prep2<<<1, 256, 0, stream>>>(gpart, bpart, b1, W2, gamma, gw1f, b1tf, w2f, gamf);
    fused_head<<<12000, 256, 0, stream>>>(final_h, future_met, b2,
                                          w1frag, sqb, wfmfrag, gw1f, b1tf, w2f, gamf, out);
}